// Round 1
// baseline (375.417 us; speedup 1.0000x reference)
//
#include <hip/hip_runtime.h>

// Dims (compile-time; N/NE/NP taken from in_sizes at runtime)
constexpr int EMB  = 128;   // EMB_DIM
constexpr int H1D  = 256;   // 2*HIDDEN
constexpr int H2D  = 128;   // HIDDEN
constexpr int VOC  = 4096;  // VOCAB

// ---------------------------------------------------------------- init
__global__ void k_init(int* cnt, int* count, float* wsum, int* nflag, int n) {
    int i = blockIdx.x * blockDim.x + threadIdx.x;
    if (i < n) { cnt[i] = 0; count[i] = 0; }
    if (i < H1D) wsum[i] = 0.0f;
    if (i == 0) *nflag = 0;
}

// ------------------------------------------------- in-degree histogram
__global__ void k_hist(const int* __restrict__ col, int* cnt, int ne) {
    int e = blockIdx.x * blockDim.x + threadIdx.x;
    if (e < ne) atomicAdd(&cnt[col[e]], 1);
}

// --------------------------------------------------------------- dinv
__global__ void k_dinv(const int* __restrict__ cnt, float* dinv, int n) {
    int i = blockIdx.x * blockDim.x + threadIdx.x;
    if (i < n) dinv[i] = rsqrtf((float)cnt[i] + 1.0f);  // +1 self loop
}

// ------------------------------------------------- 2-level exclusive scan
__global__ void k_scan_local(const int* __restrict__ cnt, int* offs, int* bsum, int n) {
    __shared__ int s[256];
    int t = threadIdx.x;
    int i = blockIdx.x * 256 + t;
    int v = (i < n) ? cnt[i] : 0;
    s[t] = v;
    __syncthreads();
    for (int off = 1; off < 256; off <<= 1) {
        int add = (t >= off) ? s[t - off] : 0;
        __syncthreads();
        s[t] += add;
        __syncthreads();
    }
    if (i < n) offs[i] = s[t] - v;          // exclusive
    if (t == 255) bsum[blockIdx.x] = s[255]; // block total
}

__global__ void k_scan_bsum(const int* __restrict__ bsum, int* boff, int nb) {
    __shared__ int s[256];
    int t = threadIdx.x;
    int v = (t < nb) ? bsum[t] : 0;
    s[t] = v;
    __syncthreads();
    for (int off = 1; off < 256; off <<= 1) {
        int add = (t >= off) ? s[t - off] : 0;
        __syncthreads();
        s[t] += add;
        __syncthreads();
    }
    boff[t] = s[t] - v;
}

__global__ void k_scan_add(int* offs, int* cursor, const int* __restrict__ boff, int n) {
    int t = threadIdx.x;
    int i = blockIdx.x * 256 + t;
    if (i < n) {
        int o = offs[i] + boff[blockIdx.x];
        offs[i] = o;
        cursor[i] = o;
    }
}

// -------------------------------------------- scatter edges into CSR order
__global__ void k_scatter(const int* __restrict__ row, const int* __restrict__ col,
                          int* cursor, int* srow, int ne) {
    int e = blockIdx.x * blockDim.x + threadIdx.x;
    if (e < ne) {
        int c = col[e];
        int pos = atomicAdd(&cursor[c], 1);
        srow[pos] = row[e];
    }
}

// --------------------------------------------- x_position multiplicities
__global__ void k_count(const int* __restrict__ xpos, int* count, int np) {
    int p = blockIdx.x * blockDim.x + threadIdx.x;
    if (p < np) atomicAdd(&count[xpos[p]], 1);
}

__global__ void k_flags(const int* __restrict__ count, int* flaglist, int* nflag, int n) {
    int v = blockIdx.x * blockDim.x + threadIdx.x;
    if (v < n && count[v] > 0) {
        int id = atomicAdd(nflag, 1);
        flaglist[id] = v;
    }
}

// ---------------------------------------------------- embW1 = emb @ W1
// one block per vocab row; 256 threads = 256 output cols
__global__ void k_embW1(const float* __restrict__ emb, const float* __restrict__ W1,
                        float* embW1) {
    __shared__ float er[EMB];
    int r = blockIdx.x;
    int t = threadIdx.x;
    if (t < EMB) er[t] = emb[r * EMB + t];
    __syncthreads();
    float acc = 0.0f;
#pragma unroll 8
    for (int k = 0; k < EMB; k++) acc += er[k] * W1[k * H1D + t];
    embW1[(size_t)r * H1D + t] = acc;
}

// --------------------------- conv1 gather: h1 = relu(Â · embW1[x] + b1)
// one wave (64 lanes) per node; lane handles float4 (4 consecutive cols)
__global__ void k_conv1(const int* __restrict__ x, const int* __restrict__ srow,
                        const int* __restrict__ offs, const int* __restrict__ cnt,
                        const float* __restrict__ dinv, const float* __restrict__ embW1,
                        const float* __restrict__ b1, float* __restrict__ h1, int n) {
    int wid  = blockIdx.x * (blockDim.x >> 6) + (threadIdx.x >> 6);
    int lane = threadIdx.x & 63;
    if (wid >= n) return;
    int v = wid;
    float dv = dinv[v];
    float4 b = ((const float4*)b1)[lane];
    const float4* self = (const float4*)(embW1 + (size_t)x[v] * H1D);
    float4 s = self[lane];
    float w0 = dv * dv;
    float4 acc;
    acc.x = b.x + w0 * s.x;
    acc.y = b.y + w0 * s.y;
    acc.z = b.z + w0 * s.z;
    acc.w = b.w + w0 * s.w;
    int start = offs[v], m = cnt[v];
    for (int e = 0; e < m; e++) {
        int r = srow[start + e];
        float w = dinv[r] * dv;
        const float4* mr = (const float4*)(embW1 + (size_t)x[r] * H1D);
        float4 t = mr[lane];
        acc.x += w * t.x;
        acc.y += w * t.y;
        acc.z += w * t.z;
        acc.w += w * t.w;
    }
    float4 o;
    o.x = fmaxf(acc.x, 0.0f);
    o.y = fmaxf(acc.y, 0.0f);
    o.z = fmaxf(acc.z, 0.0f);
    o.w = fmaxf(acc.w, 0.0f);
    ((float4*)(h1 + (size_t)v * H1D))[lane] = o;
}

// ------- conv2 collapsed: wsum[256] = sum over flagged v of
//         count[v] * ( dv^2*h1[v] + sum_{e->v} dinv[r]*dv*h1[r] )
__global__ void k_conv2(const int* __restrict__ flaglist, const int* __restrict__ nflag,
                        const int* __restrict__ count, const int* __restrict__ srow,
                        const int* __restrict__ offs, const int* __restrict__ cnt,
                        const float* __restrict__ dinv, const float* __restrict__ h1,
                        float* wsum) {
    int wpb   = blockDim.x >> 6;
    int wid   = blockIdx.x * wpb + (threadIdx.x >> 6);
    int lane  = threadIdx.x & 63;
    int nwave = gridDim.x * wpb;
    int nf    = *nflag;
    float4 acc = {0.0f, 0.0f, 0.0f, 0.0f};
    for (int i = wid; i < nf; i += nwave) {
        int v = flaglist[i];
        float cv = (float)count[v];
        float dv = dinv[v];
        const float4* hv = (const float4*)(h1 + (size_t)v * H1D);
        float4 s = hv[lane];
        float w0 = cv * dv * dv;
        acc.x += w0 * s.x;
        acc.y += w0 * s.y;
        acc.z += w0 * s.z;
        acc.w += w0 * s.w;
        int start = offs[v], m = cnt[v];
        for (int e = 0; e < m; e++) {
            int r = srow[start + e];
            float w = cv * dinv[r] * dv;
            const float4* hr = (const float4*)(h1 + (size_t)r * H1D);
            float4 t = hr[lane];
            acc.x += w * t.x;
            acc.y += w * t.y;
            acc.z += w * t.z;
            acc.w += w * t.w;
        }
    }
    int j = lane * 4;
    atomicAdd(&wsum[j + 0], acc.x);
    atomicAdd(&wsum[j + 1], acc.y);
    atomicAdd(&wsum[j + 2], acc.z);
    atomicAdd(&wsum[j + 3], acc.w);
}

// ------------------------------ zmean = (wsum @ W2)/NP + b2   (1 block, 128 thr)
__global__ void k_zmean(const float* __restrict__ wsum, const float* __restrict__ W2,
                        const float* __restrict__ b2, float* zmean, float inv_np) {
    int j = threadIdx.x;
    float acc = 0.0f;
#pragma unroll 8
    for (int k = 0; k < H1D; k++) acc += wsum[k] * W2[k * H2D + j];
    zmean[j] = b2[j] + acc * inv_np;
}

// ------------------------------ out = zmean @ Wc + bc   (16 blocks x 256)
__global__ void k_out(const float* __restrict__ zmean, const float* __restrict__ Wc,
                      const float* __restrict__ bc, float* __restrict__ out) {
    __shared__ float z[H2D];
    int t = threadIdx.x;
    if (t < H2D) z[t] = zmean[t];
    __syncthreads();
    int c = blockIdx.x * blockDim.x + t;
    float acc = bc[c];
#pragma unroll 8
    for (int j = 0; j < H2D; j++) acc += z[j] * Wc[(size_t)j * VOC + c];
    out[c] = acc;
}

extern "C" void kernel_launch(void* const* d_in, const int* in_sizes, int n_in,
                              void* d_out, int out_size, void* d_ws, size_t ws_size,
                              hipStream_t stream) {
    const int n  = in_sizes[0];
    const int ne = in_sizes[1] / 2;
    const int np = in_sizes[2];

    const int*   x    = (const int*)d_in[0];
    const int*   ei   = (const int*)d_in[1];
    const int*   xpos = (const int*)d_in[2];
    const float* emb  = (const float*)d_in[3];
    const float* W1   = (const float*)d_in[4];
    const float* b1   = (const float*)d_in[5];
    const float* W2   = (const float*)d_in[6];
    const float* b2   = (const float*)d_in[7];
    const float* Wc   = (const float*)d_in[8];
    const float* bc   = (const float*)d_in[9];
    float*       out  = (float*)d_out;

    const int* row = ei;       // edge_index[0]
    const int* col = ei + ne;  // edge_index[1]

    // workspace carve (256B aligned)
    char* p = (char*)d_ws;
    auto alloc = [&](size_t bytes) {
        char* r = p;
        p += (bytes + 255) & ~(size_t)255;
        return r;
    };
    int*   cnt      = (int*)alloc((size_t)n * 4);
    int*   offs     = (int*)alloc((size_t)n * 4);
    int*   cursor   = (int*)alloc((size_t)n * 4);
    int*   count    = (int*)alloc((size_t)n * 4);
    int*   flaglist = (int*)alloc((size_t)n * 4);
    int*   srow     = (int*)alloc((size_t)ne * 4);
    int*   bsum     = (int*)alloc(256 * 4);
    int*   boff     = (int*)alloc(256 * 4);
    int*   nflag    = (int*)alloc(256 * 4);
    float* dinv     = (float*)alloc((size_t)n * 4);
    float* embW1    = (float*)alloc((size_t)VOC * H1D * 4);
    float* h1       = (float*)alloc((size_t)n * H1D * 4);
    float* wsum     = (float*)alloc(H1D * 4);
    float* zmean    = (float*)alloc(H2D * 4);

    const int nb  = (n + 255) / 256;   // 196 scan blocks
    const int neb = (ne + 255) / 256;

    k_init<<<nb, 256, 0, stream>>>(cnt, count, wsum, nflag, n);
    k_hist<<<neb, 256, 0, stream>>>(col, cnt, ne);
    k_dinv<<<nb, 256, 0, stream>>>(cnt, dinv, n);
    k_scan_local<<<nb, 256, 0, stream>>>(cnt, offs, bsum, n);
    k_scan_bsum<<<1, 256, 0, stream>>>(bsum, boff, nb);
    k_scan_add<<<nb, 256, 0, stream>>>(offs, cursor, boff, n);
    k_scatter<<<neb, 256, 0, stream>>>(row, col, cursor, srow, ne);
    k_count<<<(np + 255) / 256, 256, 0, stream>>>(xpos, count, np);
    k_flags<<<nb, 256, 0, stream>>>(count, flaglist, nflag, n);
    k_embW1<<<VOC, 256, 0, stream>>>(emb, W1, embW1);
    k_conv1<<<(n + 3) / 4, 256, 0, stream>>>(x, srow, offs, cnt, dinv, embW1, b1, h1, n);
    k_conv2<<<64, 256, 0, stream>>>(flaglist, nflag, count, srow, offs, cnt, dinv, h1, wsum);
    k_zmean<<<1, H2D, 0, stream>>>(wsum, W2, b2, zmean, 1.0f / (float)np);
    k_out<<<VOC / 256, 256, 0, stream>>>(zmean, Wc, bc, out);
}

// Round 2
// 227.720 us; speedup vs baseline: 1.6486x; 1.6486x over previous
//
#include <hip/hip_runtime.h>

constexpr int EMB  = 128;   // EMB_DIM
constexpr int H1D  = 256;   // 2*HIDDEN
constexpr int H2D  = 128;   // HIDDEN
constexpr int VOC  = 4096;  // VOCAB

// ---------------------------------------------------------------- init
__global__ void k_init(int* cnt, int* count, float* wsum, int* nflag, int n) {
    int i = blockIdx.x * blockDim.x + threadIdx.x;
    if (i < n) { cnt[i] = 0; count[i] = 0; }
    if (i < H1D) wsum[i] = 0.0f;
    if (i == 0) *nflag = 0;
}

// ------------------------------------------------- in-degree histogram
__global__ void k_hist(const int* __restrict__ col, int* cnt, int ne) {
    int e = blockIdx.x * blockDim.x + threadIdx.x;
    if (e < ne) atomicAdd(&cnt[col[e]], 1);
}

// --------------------------------------------- x_position multiplicities
__global__ void k_count(const int* __restrict__ xpos, int* count, int np) {
    int p = blockIdx.x * blockDim.x + threadIdx.x;
    if (p < np) atomicAdd(&count[xpos[p]], 1);
}

// ------------------------- dinv + wagg self-term init (non-atomic full write)
__global__ void k_dinv(const int* __restrict__ cnt, const int* __restrict__ count,
                       float* dinv, float* wagg, int n) {
    int i = blockIdx.x * blockDim.x + threadIdx.x;
    if (i < n) {
        float d = rsqrtf((float)cnt[i] + 1.0f);  // +1 self loop
        dinv[i] = d;
        int cv = count[i];
        wagg[i] = (cv > 0) ? (float)cv * d * d : 0.0f;
    }
}

// ---------------- wagg edge contributions: wagg[row] += count[col]*dinv[col]*dinv[row]
__global__ void k_waggE(const int* __restrict__ row, const int* __restrict__ col,
                        const int* __restrict__ count, const float* __restrict__ dinv,
                        float* wagg, int ne) {
    int e = blockIdx.x * blockDim.x + threadIdx.x;
    if (e < ne) {
        int c = col[e];
        int cc = count[c];
        if (cc > 0) {
            int r = row[e];
            atomicAdd(&wagg[r], (float)cc * dinv[c] * dinv[r]);
        }
    }
}

// ------------------------------------------------- 2-level exclusive scan
__global__ void k_scan_local(const int* __restrict__ cnt, int* offs, int* bsum, int n) {
    __shared__ int s[256];
    int t = threadIdx.x;
    int i = blockIdx.x * 256 + t;
    int v = (i < n) ? cnt[i] : 0;
    s[t] = v;
    __syncthreads();
    for (int off = 1; off < 256; off <<= 1) {
        int add = (t >= off) ? s[t - off] : 0;
        __syncthreads();
        s[t] += add;
        __syncthreads();
    }
    if (i < n) offs[i] = s[t] - v;
    if (t == 255) bsum[blockIdx.x] = s[255];
}

__global__ void k_scan_bsum(const int* __restrict__ bsum, int* boff, int nb) {
    __shared__ int s[256];
    int t = threadIdx.x;
    int v = (t < nb) ? bsum[t] : 0;
    s[t] = v;
    __syncthreads();
    for (int off = 1; off < 256; off <<= 1) {
        int add = (t >= off) ? s[t - off] : 0;
        __syncthreads();
        s[t] += add;
        __syncthreads();
    }
    boff[t] = s[t] - v;
}

__global__ void k_scan_add(int* offs, int* cursor, const int* __restrict__ boff, int n) {
    int t = threadIdx.x;
    int i = blockIdx.x * 256 + t;
    if (i < n) {
        int o = offs[i] + boff[blockIdx.x];
        offs[i] = o;
        cursor[i] = o;
    }
}

// -------------------------------- needed-node list: u with wagg[u] > 0 (~17k)
__global__ void k_needlist(const float* __restrict__ wagg, int* needlist, int* nflag, int n) {
    int v = blockIdx.x * blockDim.x + threadIdx.x;
    if (v < n && wagg[v] > 0.0f) {
        int id = atomicAdd(nflag, 1);
        needlist[id] = v;
    }
}

// ---------------- scatter (filtered): only edges whose col is needed (~1/3)
__global__ void k_scatter(const int* __restrict__ row, const int* __restrict__ col,
                          const float* __restrict__ wagg, int* cursor, int* srow, int ne) {
    int e = blockIdx.x * blockDim.x + threadIdx.x;
    if (e < ne) {
        int c = col[e];
        if (wagg[c] > 0.0f) {
            int pos = atomicAdd(&cursor[c], 1);
            srow[pos] = row[e];
        }
    }
}

// ---------------------------------------------------- embW1 = emb @ W1
// 16 vocab rows per block; W1 streamed once per block (33 MB total L2 traffic)
constexpr int RPB = 16;
__global__ void k_embW1(const float* __restrict__ emb, const float* __restrict__ W1,
                        float* __restrict__ embW1) {
    __shared__ float er[RPB][EMB];   // 8 KB
    int t = threadIdx.x;             // 256 threads = output col
    int r0 = blockIdx.x * RPB;
    // cooperative load of 16x128 = 2048 floats (8 per thread, coalesced)
    for (int i = t; i < RPB * EMB; i += 256) {
        er[i / EMB][i % EMB] = emb[(size_t)r0 * EMB + i];
    }
    __syncthreads();
    float acc[RPB];
#pragma unroll
    for (int rr = 0; rr < RPB; rr++) acc[rr] = 0.0f;
    for (int k = 0; k < EMB; k++) {
        float w = W1[k * H1D + t];
#pragma unroll
        for (int rr = 0; rr < RPB; rr++) acc[rr] += er[rr][k] * w;
    }
#pragma unroll
    for (int rr = 0; rr < RPB; rr++) {
        embW1[(size_t)(r0 + rr) * H1D + t] = acc[rr];
    }
}

// -------------------- fused conv1+conv2 over needed nodes:
//   wsum[256] += wagg[v] * relu( b1 + dv^2*embW1[x[v]] + sum_e dinv[r]*dv*embW1[x[r]] )
// one wave per node (grid-stride); lanes prefetch edge indices in parallel,
// __shfl-broadcast, 4 independent row loads per unroll step.
__global__ void k_fconv(const int* __restrict__ needlist, const int* __restrict__ nneed_p,
                        const float* __restrict__ wagg, const int* __restrict__ x,
                        const int* __restrict__ srow, const int* __restrict__ offs,
                        const int* __restrict__ cnt, const float* __restrict__ dinv,
                        const float* __restrict__ embW1, const float* __restrict__ b1,
                        float* __restrict__ wsum) {
    int lane = threadIdx.x & 63;
    int wib  = threadIdx.x >> 6;                       // wave in block (0..3)
    int wid  = blockIdx.x * (blockDim.x >> 6) + wib;
    int nw   = gridDim.x * (blockDim.x >> 6);
    int nn   = *nneed_p;
    const float4* __restrict__ ew = (const float4*)embW1;   // row r = ew + r*64
    float4 bfrag = ((const float4*)b1)[lane];
    float4 acc2 = {0.0f, 0.0f, 0.0f, 0.0f};

    for (int i = wid; i < nn; i += nw) {
        int v = needlist[i];
        float dv = dinv[v];
        float wa = wagg[v];
        float4 s = ew[(size_t)x[v] * 64 + lane];
        float w0 = dv * dv;
        float4 acc;
        acc.x = bfrag.x + w0 * s.x;
        acc.y = bfrag.y + w0 * s.y;
        acc.z = bfrag.z + w0 * s.z;
        acc.w = bfrag.w + w0 * s.w;
        int start = offs[v], m = cnt[v];
        for (int base = 0; base < m; base += 64) {
            int mm = min(64, m - base);
            // lane-parallel index prefetch (breaks the serial dependent chain)
            int xr = 0; float wr = 0.0f;
            if (lane < mm) {
                int r = srow[start + base + lane];
                xr = x[r];
                wr = dinv[r] * dv;
            }
            int e = 0;
            for (; e + 4 <= mm; e += 4) {
                int i0 = __shfl(xr, e),     i1 = __shfl(xr, e + 1);
                int i2 = __shfl(xr, e + 2), i3 = __shfl(xr, e + 3);
                float q0 = __shfl(wr, e),     q1 = __shfl(wr, e + 1);
                float q2 = __shfl(wr, e + 2), q3 = __shfl(wr, e + 3);
                float4 t0 = ew[(size_t)i0 * 64 + lane];
                float4 t1 = ew[(size_t)i1 * 64 + lane];
                float4 t2 = ew[(size_t)i2 * 64 + lane];
                float4 t3 = ew[(size_t)i3 * 64 + lane];
                acc.x += q0 * t0.x + q1 * t1.x + q2 * t2.x + q3 * t3.x;
                acc.y += q0 * t0.y + q1 * t1.y + q2 * t2.y + q3 * t3.y;
                acc.z += q0 * t0.z + q1 * t1.z + q2 * t2.z + q3 * t3.z;
                acc.w += q0 * t0.w + q1 * t1.w + q2 * t2.w + q3 * t3.w;
            }
            for (; e < mm; e++) {
                int i0 = __shfl(xr, e);
                float q0 = __shfl(wr, e);
                float4 t0 = ew[(size_t)i0 * 64 + lane];
                acc.x += q0 * t0.x;
                acc.y += q0 * t0.y;
                acc.z += q0 * t0.z;
                acc.w += q0 * t0.w;
            }
        }
        acc2.x += wa * fmaxf(acc.x, 0.0f);
        acc2.y += wa * fmaxf(acc.y, 0.0f);
        acc2.z += wa * fmaxf(acc.z, 0.0f);
        acc2.w += wa * fmaxf(acc.w, 0.0f);
    }

    // block reduction: 4 waves x 256 cols in LDS, then one atomic per col per block
    __shared__ float red[4][H1D];
    red[wib][4 * lane + 0] = acc2.x;
    red[wib][4 * lane + 1] = acc2.y;
    red[wib][4 * lane + 2] = acc2.z;
    red[wib][4 * lane + 3] = acc2.w;
    __syncthreads();
    int t = threadIdx.x;
    float ssum = red[0][t] + red[1][t] + red[2][t] + red[3][t];
    atomicAdd(&wsum[t], ssum);
}

// ------------------------------ zmean = (wsum @ W2)/NP + b2   (1 block, 128 thr)
__global__ void k_zmean(const float* __restrict__ wsum, const float* __restrict__ W2,
                        const float* __restrict__ b2, float* zmean, float inv_np) {
    int j = threadIdx.x;
    float acc = 0.0f;
#pragma unroll 8
    for (int k = 0; k < H1D; k++) acc += wsum[k] * W2[k * H2D + j];
    zmean[j] = b2[j] + acc * inv_np;
}

// ------------------------------ out = zmean @ Wc + bc   (16 blocks x 256)
__global__ void k_out(const float* __restrict__ zmean, const float* __restrict__ Wc,
                      const float* __restrict__ bc, float* __restrict__ out) {
    __shared__ float z[H2D];
    int t = threadIdx.x;
    if (t < H2D) z[t] = zmean[t];
    __syncthreads();
    int c = blockIdx.x * blockDim.x + t;
    float acc = bc[c];
#pragma unroll 8
    for (int j = 0; j < H2D; j++) acc += z[j] * Wc[(size_t)j * VOC + c];
    out[c] = acc;
}

extern "C" void kernel_launch(void* const* d_in, const int* in_sizes, int n_in,
                              void* d_out, int out_size, void* d_ws, size_t ws_size,
                              hipStream_t stream) {
    const int n  = in_sizes[0];
    const int ne = in_sizes[1] / 2;
    const int np = in_sizes[2];

    const int*   x    = (const int*)d_in[0];
    const int*   ei   = (const int*)d_in[1];
    const int*   xpos = (const int*)d_in[2];
    const float* emb  = (const float*)d_in[3];
    const float* W1   = (const float*)d_in[4];
    const float* b1   = (const float*)d_in[5];
    const float* W2   = (const float*)d_in[6];
    const float* b2   = (const float*)d_in[7];
    const float* Wc   = (const float*)d_in[8];
    const float* bc   = (const float*)d_in[9];
    float*       out  = (float*)d_out;

    const int* row = ei;       // edge_index[0]
    const int* col = ei + ne;  // edge_index[1]

    char* p = (char*)d_ws;
    auto alloc = [&](size_t bytes) {
        char* r = p;
        p += (bytes + 255) & ~(size_t)255;
        return r;
    };
    int*   cnt      = (int*)alloc((size_t)n * 4);
    int*   offs     = (int*)alloc((size_t)n * 4);
    int*   cursor   = (int*)alloc((size_t)n * 4);
    int*   count    = (int*)alloc((size_t)n * 4);
    int*   needlist = (int*)alloc((size_t)n * 4);
    int*   srow     = (int*)alloc((size_t)ne * 4);
    int*   bsum     = (int*)alloc(256 * 4);
    int*   boff     = (int*)alloc(256 * 4);
    int*   nflag    = (int*)alloc(256 * 4);
    float* dinv     = (float*)alloc((size_t)n * 4);
    float* wagg     = (float*)alloc((size_t)n * 4);
    float* embW1    = (float*)alloc((size_t)VOC * H1D * 4);
    float* wsum     = (float*)alloc(H1D * 4);
    float* zmean    = (float*)alloc(H2D * 4);

    const int nb  = (n + 255) / 256;
    const int neb = (ne + 255) / 256;

    k_init<<<nb, 256, 0, stream>>>(cnt, count, wsum, nflag, n);
    k_hist<<<neb, 256, 0, stream>>>(col, cnt, ne);
    k_count<<<(np + 255) / 256, 256, 0, stream>>>(xpos, count, np);
    k_dinv<<<nb, 256, 0, stream>>>(cnt, count, dinv, wagg, n);
    k_waggE<<<neb, 256, 0, stream>>>(row, col, count, dinv, wagg, ne);
    k_scan_local<<<nb, 256, 0, stream>>>(cnt, offs, bsum, n);
    k_scan_bsum<<<1, 256, 0, stream>>>(bsum, boff, nb);
    k_scan_add<<<nb, 256, 0, stream>>>(offs, cursor, boff, n);
    k_needlist<<<nb, 256, 0, stream>>>(wagg, needlist, nflag, n);
    k_scatter<<<neb, 256, 0, stream>>>(row, col, wagg, cursor, srow, ne);
    k_embW1<<<VOC / RPB, 256, 0, stream>>>(emb, W1, embW1);
    k_fconv<<<512, 256, 0, stream>>>(needlist, nflag, wagg, x, srow, offs, cnt,
                                     dinv, embW1, b1, wsum);
    k_zmean<<<1, H2D, 0, stream>>>(wsum, W2, b2, zmean, 1.0f / (float)np);
    k_out<<<VOC / 256, 256, 0, stream>>>(zmean, Wc, bc, out);
}